// Round 1
// baseline (278.965 us; speedup 1.0000x reference)
//
#include <hip/hip_runtime.h>

#define SS 512
#define BB 512
#define TT 64
#define NTHREADS 256

// One block per batch element. 4 waves; thread tid -> (j = tid>>2, li = tid&3).
// Lane (j,li) covers source tags i in [li*16, li*16+16).
// Forward Viterbi with history in LDS, then in-LDS backtrace.
__global__ __launch_bounds__(NTHREADS) void viterbi_fused(
    const float* __restrict__ feats,   // (S,B,T)
    const float* __restrict__ mask,    // (B,S)
    const float* __restrict__ startt,  // (T,)
    const float* __restrict__ endt,    // (T,)
    const float* __restrict__ trans,   // (T,T)
    int* __restrict__ out)             // (B,S)
{
    __shared__ float vbuf[2][TT];
    __shared__ unsigned char hist[SS - 1][TT];
    __shared__ float redbuf[4];
    __shared__ int lenSh;

    const int b   = blockIdx.x;
    const int tid = threadIdx.x;
    const int j   = tid >> 2;
    const int li  = tid & 3;
    const int base_i = li * 16;
    const int wid = tid >> 6;
    const int lane = tid & 63;

    // ---- sequence length: sum of mask row (exact small-int fp32 adds) ----
    float msum = mask[b * SS + tid] + mask[b * SS + 256 + tid];
#pragma unroll
    for (int off = 1; off < 64; off <<= 1) msum += __shfl_xor(msum, off);
    if (lane == 0) redbuf[wid] = msum;
    __syncthreads();
    if (tid == 0) {
        float t = redbuf[0] + redbuf[1] + redbuf[2] + redbuf[3];
        lenSh = (int)(t + 0.5f);
    }

    // ---- transitions column slice into registers ----
    float tc[16];
#pragma unroll
    for (int k = 0; k < 16; ++k) tc[k] = trans[(base_i + k) * TT + j];

    // ---- init: score0 = start + feats[0] ----
    if (tid < TT) vbuf[0][tid] = startt[tid] + feats[(size_t)b * TT + tid];
    __syncthreads();

    const int len = lenSh;
    int p = 0;

    const float* fb = feats + (size_t)b * TT + j;   // per-thread emis pointer
    float e_cur = fb[(size_t)1 * (BB * TT)];

    for (int s = 1; s < len; ++s) {
        const int sn = (s + 1 < SS) ? (s + 1) : s;
        float e_next = fb[(size_t)sn * (BB * TT)];

        // read vscore slice [base_i, base_i+16)
        float v[16];
#pragma unroll
        for (int q = 0; q < 4; ++q) {
            float4 t4 = *(const float4*)&vbuf[p][base_i + q * 4];
            v[q * 4 + 0] = t4.x; v[q * 4 + 1] = t4.y;
            v[q * 4 + 2] = t4.z; v[q * 4 + 3] = t4.w;
        }

        float best = -3.402823466e38f;
        int   bi   = base_i;
#pragma unroll
        for (int k = 0; k < 16; ++k) {
            float sc = (v[k] + tc[k]) + e_cur;   // match reference association order
            if (sc > best) { best = sc; bi = base_i + k; }
        }

        // combine the 4 lanes of this j (first-max tie rule via smaller index)
#pragma unroll
        for (int off = 1; off < 4; off <<= 1) {
            float ov = __shfl_xor(best, off);
            int   oi = __shfl_xor(bi, off);
            if (ov > best || (ov == best && oi < bi)) { best = ov; bi = oi; }
        }

        if (li == 0) {
            vbuf[p ^ 1][j] = best;               // mask==1 here: new_v = best exactly
            hist[s - 1][j] = (unsigned char)bi;
        }
        __syncthreads();
        p ^= 1;
        e_cur = e_next;
    }

    // ---- final argmax + backtrace (wave 0) ----
    if (tid < TT) {
        float fv = vbuf[p][tid] + endt[tid];
        int bix = tid;
#pragma unroll
        for (int off = 1; off < 64; off <<= 1) {
            float ov = __shfl_xor(fv, off);
            int   oi = __shfl_xor(bix, off);
            if (ov > fv || (ov == fv && oi < bix)) { fv = ov; bix = oi; }
        }
        if (tid == 0) {
            int* ob = out + (size_t)b * SS;
            int cur = bix;
            ob[SS - 1] = cur;      // decode[S-1] = last_path always
            ob[len - 1] = cur;     // position len-1 = last_path
            for (int s2 = len - 2; s2 >= 0; --s2) {
                cur = hist[s2][cur];
                ob[s2] = cur;
            }
        }
    }

    // zeros for masked region s in [len, S-2]
    for (int s2 = len + tid; s2 < SS - 1; s2 += NTHREADS)
        out[(size_t)b * SS + s2] = 0;
}

extern "C" void kernel_launch(void* const* d_in, const int* in_sizes, int n_in,
                              void* d_out, int out_size, void* d_ws, size_t ws_size,
                              hipStream_t stream) {
    const float* feats  = (const float*)d_in[0];
    const float* mask   = (const float*)d_in[1];
    const float* startt = (const float*)d_in[2];
    const float* endt   = (const float*)d_in[3];
    const float* trans  = (const float*)d_in[4];
    int* out = (int*)d_out;

    viterbi_fused<<<dim3(BB), dim3(NTHREADS), 0, stream>>>(
        feats, mask, startt, endt, trans, out);
}

// Round 2
// 260.910 us; speedup vs baseline: 1.0692x; 1.0692x over previous
//
#include <hip/hip_runtime.h>

#define SS 512
#define BB 512
#define TT 64
#define NTHREADS 256
#define FSTRIDE ((size_t)BB * TT)

// DPP quad_perm helpers: exchange within groups of 4 lanes (1 VALU op, no LDS).
// ctrl = perm[0] | perm[1]<<2 | perm[2]<<4 | perm[3]<<6
// xor1 -> [1,0,3,2] = 0xB1 ; xor2 -> [2,3,0,1] = 0x4E
template <int CTRL>
__device__ __forceinline__ float dppf(float x) {
    return __int_as_float(__builtin_amdgcn_mov_dpp(__float_as_int(x), CTRL, 0xF, 0xF, true));
}
template <int CTRL>
__device__ __forceinline__ int dppi(int x) {
    return __builtin_amdgcn_mov_dpp(x, CTRL, 0xF, 0xF, true);
}

// One block per batch element. 4 waves; thread tid -> (j = tid>>2, li = tid&3).
// Lane (j,li) covers source tags i in [li*16, li*16+16).
// Forward Viterbi with history in LDS, then in-LDS backtrace.
__global__ __launch_bounds__(NTHREADS) void viterbi_fused(
    const float* __restrict__ feats,   // (S,B,T)
    const float* __restrict__ mask,    // (B,S)
    const float* __restrict__ startt,  // (T,)
    const float* __restrict__ endt,    // (T,)
    const float* __restrict__ trans,   // (T,T)
    int* __restrict__ out)             // (B,S)
{
    __shared__ float vbuf[2][TT];
    __shared__ unsigned char hist[SS - 1][TT];
    __shared__ float redbuf[4];
    __shared__ int lenSh;

    const int b   = blockIdx.x;
    const int tid = threadIdx.x;
    const int j   = tid >> 2;
    const int li  = tid & 3;
    const int base_i = li * 16;
    const int wid = tid >> 6;
    const int lane = tid & 63;

    // ---- sequence length: sum of mask row (exact small-int fp32 adds) ----
    float msum = mask[b * SS + tid] + mask[b * SS + 256 + tid];
#pragma unroll
    for (int off = 1; off < 64; off <<= 1) msum += __shfl_xor(msum, off);
    if (lane == 0) redbuf[wid] = msum;
    __syncthreads();
    if (tid == 0) {
        float t = redbuf[0] + redbuf[1] + redbuf[2] + redbuf[3];
        lenSh = (int)(t + 0.5f);
    }

    // ---- transitions column slice into registers ----
    float tcr[16];
#pragma unroll
    for (int k = 0; k < 16; ++k) tcr[k] = trans[(base_i + k) * TT + j];

    // ---- init: score0 = start + feats[0] ----
    if (tid < TT) vbuf[0][tid] = startt[tid] + feats[(size_t)b * TT + tid];
    __syncthreads();

    const int len = lenSh;
    int p = 0;

    const float* fb = feats + (size_t)b * TT + j;   // per-thread emis pointer
    // depth-2 prefetch of emissions (global latency ~500cy > step time)
    float e0 = fb[1 * FSTRIDE];
    float e1 = fb[2 * FSTRIDE];

    for (int s = 1; s < len; ++s) {
        int sn = s + 2; if (sn > SS - 1) sn = SS - 1;
        float e_pre = fb[(size_t)sn * FSTRIDE];

        // read vscore slice [base_i, base_i+16)
        float v[16];
#pragma unroll
        for (int q = 0; q < 4; ++q) {
            float4 t4 = *(const float4*)&vbuf[p][base_i + q * 4];
            v[q * 4 + 0] = t4.x; v[q * 4 + 1] = t4.y;
            v[q * 4 + 2] = t4.z; v[q * 4 + 3] = t4.w;
        }

        // scores, exact reference association: (v + trans) + emis
        float sc[16];
#pragma unroll
        for (int k = 0; k < 16; ++k) sc[k] = (v[k] + tcr[k]) + e0;

        // argmax over 16 candidates: 4 independent chains + tree merge.
        // Strict '>' everywhere, lower-index side kept on ties -> first-index
        // rule, bit-identical to a sequential first-max scan.
        float c0 = sc[0];  int x0 = 0;
        float c1 = sc[4];  int x1 = 4;
        float c2 = sc[8];  int x2 = 8;
        float c3 = sc[12]; int x3 = 12;
#pragma unroll
        for (int k = 1; k < 4; ++k) {
            if (sc[k]      > c0) { c0 = sc[k];      x0 = k; }
            if (sc[4 + k]  > c1) { c1 = sc[4 + k];  x1 = 4 + k; }
            if (sc[8 + k]  > c2) { c2 = sc[8 + k];  x2 = 8 + k; }
            if (sc[12 + k] > c3) { c3 = sc[12 + k]; x3 = 12 + k; }
        }
        if (c1 > c0) { c0 = c1; x0 = x1; }
        if (c3 > c2) { c2 = c3; x2 = x3; }
        if (c2 > c0) { c0 = c2; x0 = x2; }
        float best = c0;
        int   bi   = base_i + x0;

        // combine the 4 lanes of this j via DPP quad_perm (no LDS latency)
        {
            float ov = dppf<0xB1>(best);
            int   oi = dppi<0xB1>(bi);
            if (ov > best || (ov == best && oi < bi)) { best = ov; bi = oi; }
            ov = dppf<0x4E>(best);
            oi = dppi<0x4E>(bi);
            if (ov > best || (ov == best && oi < bi)) { best = ov; bi = oi; }
        }

        if (li == 0) {
            vbuf[p ^ 1][j] = best;               // mask==1 here: new_v = best exactly
            hist[s - 1][j] = (unsigned char)bi;
        }
        __syncthreads();
        p ^= 1;
        e0 = e1;
        e1 = e_pre;
    }

    // ---- final argmax + backtrace (wave 0) ----
    if (tid < TT) {
        float fv = vbuf[p][tid] + endt[tid];
        int bix = tid;
#pragma unroll
        for (int off = 1; off < 64; off <<= 1) {
            float ov = __shfl_xor(fv, off);
            int   oi = __shfl_xor(bix, off);
            if (ov > fv || (ov == fv && oi < bix)) { fv = ov; bix = oi; }
        }
        if (tid == 0) {
            int* ob = out + (size_t)b * SS;
            int cur = bix;
            ob[SS - 1] = cur;      // decode[S-1] = last_path always
            ob[len - 1] = cur;     // position len-1 = last_path
            for (int s2 = len - 2; s2 >= 0; --s2) {
                cur = hist[s2][cur];
                ob[s2] = cur;
            }
        }
    }

    // zeros for masked region s in [len, S-2]
    for (int s2 = len + tid; s2 < SS - 1; s2 += NTHREADS)
        out[(size_t)b * SS + s2] = 0;
}

extern "C" void kernel_launch(void* const* d_in, const int* in_sizes, int n_in,
                              void* d_out, int out_size, void* d_ws, size_t ws_size,
                              hipStream_t stream) {
    const float* feats  = (const float*)d_in[0];
    const float* mask   = (const float*)d_in[1];
    const float* startt = (const float*)d_in[2];
    const float* endt   = (const float*)d_in[3];
    const float* trans  = (const float*)d_in[4];
    int* out = (int*)d_out;

    viterbi_fused<<<dim3(BB), dim3(NTHREADS), 0, stream>>>(
        feats, mask, startt, endt, trans, out);
}

// Round 3
// 255.806 us; speedup vs baseline: 1.0905x; 1.0200x over previous
//
#include <hip/hip_runtime.h>

#define SS 512
#define BB 512
#define TT 64
#define NTHREADS 256
#define FSTRIDE ((size_t)BB * TT)

// DPP quad_perm helpers: exchange within groups of 4 lanes (1 VALU op, no LDS).
// xor1 -> [1,0,3,2] = 0xB1 ; xor2 -> [2,3,0,1] = 0x4E
template <int CTRL>
__device__ __forceinline__ float dppf(float x) {
    return __int_as_float(__builtin_amdgcn_mov_dpp(__float_as_int(x), CTRL, 0xF, 0xF, true));
}
template <int CTRL>
__device__ __forceinline__ int dppi(int x) {
    return __builtin_amdgcn_mov_dpp(x, CTRL, 0xF, 0xF, true);
}

// Raw barrier: drain LDS ops (cross-wave vbuf visibility) but do NOT drain
// vmcnt -- emissions prefetch loads stay in flight across the barrier.
// (__syncthreads would emit s_waitcnt vmcnt(0) and expose global latency.)
__device__ __forceinline__ void barrier_lgkm() {
    asm volatile("s_waitcnt lgkmcnt(0)\n\ts_barrier" ::: "memory");
}

// One block per batch element. 4 waves; tid -> (j = tid>>2, li = tid&3).
// Lane (j,li) covers source tags i in [li*16, li*16+16).
__global__ __launch_bounds__(NTHREADS) void viterbi_fused(
    const float* __restrict__ feats,   // (S,B,T)
    const float* __restrict__ mask,    // (B,S)
    const float* __restrict__ startt,  // (T,)
    const float* __restrict__ endt,    // (T,)
    const float* __restrict__ trans,   // (T,T)
    int* __restrict__ out)             // (B,S)
{
    __shared__ float vbuf[2][TT];
    __shared__ unsigned char hist[SS - 1][TT];
    __shared__ float redbuf[4];
    __shared__ int lenSh;

    const int b   = blockIdx.x;
    const int tid = threadIdx.x;
    const int j   = tid >> 2;
    const int li  = tid & 3;
    const int base_i = li * 16;
    const int wid = tid >> 6;
    const int lane = tid & 63;

    // ---- transitions column slice into registers (issue early) ----
    float tcr[16];
#pragma unroll
    for (int k = 0; k < 16; ++k) tcr[k] = trans[(base_i + k) * TT + j];

    // ---- init: score0 = start + feats[0] ----
    if (tid < TT) vbuf[0][tid] = startt[tid] + feats[(size_t)b * TT + tid];

    // ---- sequence length: sum of mask row ----
    float msum = mask[b * SS + tid] + mask[b * SS + 256 + tid];
#pragma unroll
    for (int off = 1; off < 64; off <<= 1) msum += __shfl_xor(msum, off);
    if (lane == 0) redbuf[wid] = msum;
    __syncthreads();
    if (tid == 0) {
        float t = redbuf[0] + redbuf[1] + redbuf[2] + redbuf[3];
        lenSh = (int)(t + 0.5f);
    }
    __syncthreads();

    const int len = lenSh;
    int p = 0;

    const float* fb = feats + (size_t)b * TT + j;   // per-thread emis pointer

    // step body: scores, 16-candidate argmax (first-index tie rule), DPP
    // combine across the 4 lanes of j, vbuf/hist update, raw barrier.
    auto body = [&](float e, int s) {
        float v[16];
#pragma unroll
        for (int q = 0; q < 4; ++q) {
            float4 t4 = *(const float4*)&vbuf[p][base_i + q * 4];
            v[q * 4 + 0] = t4.x; v[q * 4 + 1] = t4.y;
            v[q * 4 + 2] = t4.z; v[q * 4 + 3] = t4.w;
        }
        float sc[16];
#pragma unroll
        for (int k = 0; k < 16; ++k) sc[k] = (v[k] + tcr[k]) + e;

        // 4 independent chains + tree merge; strict '>' + lower-index-on-tie
        // everywhere == sequential first-max scan, bit-exact.
        float c0 = sc[0];  int x0 = 0;
        float c1 = sc[4];  int x1 = 4;
        float c2 = sc[8];  int x2 = 8;
        float c3 = sc[12]; int x3 = 12;
#pragma unroll
        for (int k = 1; k < 4; ++k) {
            if (sc[k]      > c0) { c0 = sc[k];      x0 = k; }
            if (sc[4 + k]  > c1) { c1 = sc[4 + k];  x1 = 4 + k; }
            if (sc[8 + k]  > c2) { c2 = sc[8 + k];  x2 = 8 + k; }
            if (sc[12 + k] > c3) { c3 = sc[12 + k]; x3 = 12 + k; }
        }
        if (c1 > c0) { c0 = c1; x0 = x1; }
        if (c3 > c2) { c2 = c3; x2 = x3; }
        if (c2 > c0) { c0 = c2; x0 = x2; }
        float best = c0;
        int   bi   = base_i + x0;

        {
            float ov = dppf<0xB1>(best);
            int   oi = dppi<0xB1>(bi);
            if (ov > best || (ov == best && oi < bi)) { best = ov; bi = oi; }
            ov = dppf<0x4E>(best);
            oi = dppi<0x4E>(bi);
            if (ov > best || (ov == best && oi < bi)) { best = ov; bi = oi; }
        }

        if (li == 0) {
            vbuf[p ^ 1][j] = best;               // mask==1 here: new_v = best
            hist[s - 1][j] = (unsigned char)bi;
        }
        barrier_lgkm();
        p ^= 1;
    };

    // ---- emissions: chunked prefetch, 8 steps ahead, static reg indexing ----
    float ec[8], en[8];
#pragma unroll
    for (int u = 0; u < 8; ++u) {
        int sn = 1 + u; if (sn > SS - 1) sn = SS - 1;
        ec[u] = fb[(size_t)sn * FSTRIDE];
    }

    int s = 1;
    while (s + 8 <= len) {
        // issue next chunk's loads (stay in flight across 8 raw barriers)
#pragma unroll
        for (int u = 0; u < 8; ++u) {
            int sn = s + 8 + u; if (sn > SS - 1) sn = SS - 1;
            en[u] = fb[(size_t)sn * FSTRIDE];
        }
#pragma unroll
        for (int u = 0; u < 8; ++u) body(ec[u], s + u);
#pragma unroll
        for (int u = 0; u < 8; ++u) ec[u] = en[u];
        s += 8;
    }
    // tail (< 8 steps), uniform branches
#pragma unroll
    for (int u = 0; u < 7; ++u) {
        if (s + u < len) body(ec[u], s + u);
    }

    // ---- final argmax + backtrace (wave 0) ----
    if (tid < TT) {
        float fv = vbuf[p][tid] + endt[tid];
        int bix = tid;
#pragma unroll
        for (int off = 1; off < 64; off <<= 1) {
            float ov = __shfl_xor(fv, off);
            int   oi = __shfl_xor(bix, off);
            if (ov > fv || (ov == fv && oi < bix)) { fv = ov; bix = oi; }
        }
        if (tid == 0) {
            int* ob = out + (size_t)b * SS;
            int cur = bix;
            ob[SS - 1] = cur;      // decode[S-1] = last_path always
            ob[len - 1] = cur;     // position len-1 = last_path
            for (int s2 = len - 2; s2 >= 0; --s2) {
                cur = hist[s2][cur];
                ob[s2] = cur;
            }
        }
    }

    // zeros for masked region s in [len, S-2]
    for (int s2 = len + tid; s2 < SS - 1; s2 += NTHREADS)
        out[(size_t)b * SS + s2] = 0;
}

extern "C" void kernel_launch(void* const* d_in, const int* in_sizes, int n_in,
                              void* d_out, int out_size, void* d_ws, size_t ws_size,
                              hipStream_t stream) {
    const float* feats  = (const float*)d_in[0];
    const float* mask   = (const float*)d_in[1];
    const float* startt = (const float*)d_in[2];
    const float* endt   = (const float*)d_in[3];
    const float* trans  = (const float*)d_in[4];
    int* out = (int*)d_out;

    viterbi_fused<<<dim3(BB), dim3(NTHREADS), 0, stream>>>(
        feats, mask, startt, endt, trans, out);
}